// Round 14
// baseline (210.610 us; speedup 1.0000x reference)
//
#include <hip/hip_runtime.h>
#include <hip/hip_bf16.h>

typedef __bf16 bf16;
typedef __bf16 bf16x4 __attribute__((ext_vector_type(4)));
typedef __bf16 bf16x8 __attribute__((ext_vector_type(8)));
typedef float f32x4 __attribute__((ext_vector_type(4)));

#define GLP(p) ((const __attribute__((address_space(1))) void*)(p))
#define LDSP(p) ((__attribute__((address_space(3))) void*)(p))

// ---------------- fused fp32 -> bf16 convert (hs + Wq + Wk + Wv) ----------
__global__ __launch_bounds__(256) void cvt_all_kernel(
    const float* __restrict__ hs, const float* __restrict__ Wq,
    const float* __restrict__ Wk, const float* __restrict__ Wv,
    bf16* __restrict__ Xb, bf16* __restrict__ Wb) {
  int i = blockIdx.x * 256 + threadIdx.x;  // < 1835008
  const float* src;
  bf16* dst;
  int off;
  if (i < 1048576) {
    src = hs; dst = Xb; off = i;
  } else {
    int j = i - 1048576;
    int which = j >> 18;          // 0..2
    off = j & 262143;
    src = (which == 0) ? Wq : (which == 1) ? Wk : Wv;
    dst = Wb + (which << 20);     // 1048576 bf16 elems per W slab
  }
  float4 v = *reinterpret_cast<const float4*>(src + off * 4);
  bf16x4 o = { (bf16)v.x, (bf16)v.y, (bf16)v.z, (bf16)v.w };
  *reinterpret_cast<bf16x4*>(dst + off * 4) = o;
}

// ---------------- fused QKV GEMM (BK=64, swizzled LDS) ----------------
// C[4096,3072] = Xb[4096,1024] @ Wb[3072,1024]^T + bias
// LDS tiles [128][64] bf16 (128B rows): chunk c of row r stored at slot c^(r&7)
// via pre-swizzled global source; ds_read applies same XOR (r&7 == lr&7).
__global__ __launch_bounds__(256) void qkv_gemm(
    const bf16* __restrict__ Xb, const bf16* __restrict__ Wb,
    const float* __restrict__ biasq, const float* __restrict__ biask,
    const float* __restrict__ biasv,
    bf16* __restrict__ Qb, bf16* __restrict__ Kb, bf16* __restrict__ Vt) {
  __shared__ __align__(16) bf16 As[128 * 64];
  __shared__ __align__(16) bf16 Bs[128 * 64];
  const int tid = threadIdx.x;
  const int w = tid >> 6, l = tid & 63;
  const int lg = l >> 4, lr = l & 15;
  const int wr = w >> 1, wc = w & 1;
  const int bm = blockIdx.y * 128, bn = blockIdx.x * 128;

  f32x4 acc[4][4] = {};

  #pragma unroll 1
  for (int k0 = 0; k0 < 1024; k0 += 64) {
    // stage As,Bs: 1024 chunks each, 4 per thread, source-swizzled
    #pragma unroll
    for (int p = 0; p < 4; ++p) {
      int cl = p * 256 + tid;
      int row = cl >> 3, sch = cl & 7;
      int cg = (sch ^ (row & 7)) * 8;
      __builtin_amdgcn_global_load_lds(GLP(Xb + (bm + row) * 1024 + k0 + cg),
                                       LDSP((char*)As + (p * 256 + w * 64) * 16), 16, 0, 0);
      __builtin_amdgcn_global_load_lds(GLP(Wb + (bn + row) * 1024 + k0 + cg),
                                       LDSP((char*)Bs + (p * 256 + w * 64) * 16), 16, 0, 0);
    }
    __syncthreads();
    #pragma unroll
    for (int kk = 0; kk < 2; ++kk) {
      bf16x8 af[4], bfq[4];
      #pragma unroll
      for (int t = 0; t < 4; ++t) {
        int arow = wr * 64 + t * 16 + lr;
        int brow = wc * 64 + t * 16 + lr;
        int slot = ((kk * 4 + lg) ^ (lr & 7)) * 16;
        af[t]  = *reinterpret_cast<const bf16x8*>(
                     reinterpret_cast<const char*>(As) + arow * 128 + slot);
        bfq[t] = *reinterpret_cast<const bf16x8*>(
                     reinterpret_cast<const char*>(Bs) + brow * 128 + slot);
      }
      #pragma unroll
      for (int mt = 0; mt < 4; ++mt)
        #pragma unroll
        for (int nt = 0; nt < 4; ++nt)
          acc[mt][nt] = __builtin_amdgcn_mfma_f32_16x16x32_bf16(af[mt], bfq[nt], acc[mt][nt], 0, 0, 0);
    }
    __syncthreads();
  }

  // epilogue: block's n-range lies entirely in one of {Q,K,V} (1024 % 128 == 0)
  const int mtx = blockIdx.x >> 3;
  const float* bp = (mtx == 0) ? biasq : (mtx == 1) ? biask : biasv;
  const float scale = (mtx == 0) ? 0.18033688f : 1.0f;  // Q: 0.125 * log2(e)
  #pragma unroll
  for (int nt = 0; nt < 4; ++nt) {
    int ng = bn + wc * 64 + nt * 16 + lr;
    int nj = ng & 1023;
    int hh = nj >> 6, d = nj & 63;
    float bias = bp[nj];
    #pragma unroll
    for (int mt = 0; mt < 4; ++mt) {
      int m0 = bm + wr * 64 + mt * 16 + lg * 4;
      int bb = m0 >> 11, s0 = m0 & 2047;
      if (mtx == 2) {
        bf16x4 pk;
        #pragma unroll
        for (int r = 0; r < 4; ++r) pk[r] = (bf16)(acc[mt][nt][r] + bias);
        *reinterpret_cast<bf16x4*>(Vt + (((bb * 16 + hh) * 64 + d) * 2048 + s0)) = pk;
      } else {
        bf16* dst = (mtx == 0) ? Qb : Kb;
        #pragma unroll
        for (int r = 0; r < 4; ++r)
          dst[((bb * 16 + hh) * 2048 + s0 + r) * 64 + d] = (bf16)((acc[mt][nt][r] + bias) * scale);
      }
    }
  }
}

// ---------------- flash attention (KVBLK=128, LDS-staged, swapped QK^T) ----
// Q,K: [BH][2048][64] bf16 ; Vt: [BH][64][2048] bf16 ; out fp32 [B][S][NH][64]
// K tile [128][64] (128B rows, 8-slot swizzle); V tile [64][128] (256B rows,
// 16-slot swizzle). Q pre-scaled by 1/8*log2e. Mask hoisted; defer-max THR=8.
__global__ __launch_bounds__(256) void attn_kernel(
    const bf16* __restrict__ Qb, const bf16* __restrict__ Kb,
    const bf16* __restrict__ Vt, const float* __restrict__ mask,
    float* __restrict__ out) {
  __shared__ __align__(16) bf16 Ks[128 * 64];     // 16 KB K tile [kv][d]
  __shared__ __align__(16) bf16 Vs[64 * 128];     // 16 KB V tile [d][kv]
  __shared__ __align__(16) bf16 Pl[4][16 * 136];  // per-wave P tile, stride 136
  const int tid = threadIdx.x;
  const int w = tid >> 6, l = tid & 63;
  const int lg = l >> 4, lr = l & 15;
  const int blk = blockIdx.x;
  const int xcd = blk & 7, i0 = blk >> 3;
  const int bh = xcd * 4 + (i0 >> 5), qt = i0 & 31;
  const int bb = bh >> 4, hh = bh & 15;
  const int q16 = qt * 64 + w * 16;

  const bf16* Qp = Qb + (bh * 2048 + q16) * 64;
  const bf16* Kp = Kb + bh * 2048 * 64;
  const bf16* Vp = Vt + bh * 64 * 2048;
  const float* mp = mask + bb * 2048;

  // prologue: does this batch's mask have any zero?
  bool nm = false;
  #pragma unroll
  for (int i = 0; i < 8; ++i) {
    float4 mv = *reinterpret_cast<const float4*>(mp + i * 256 + l * 4);
    nm |= (mv.x != 1.f) | (mv.y != 1.f) | (mv.z != 1.f) | (mv.w != 1.f);
  }
  const bool need_mask = __any(nm);

  bf16x8 aq[2];
  #pragma unroll
  for (int kk = 0; kk < 2; ++kk)
    aq[kk] = *reinterpret_cast<const bf16x8*>(Qp + lr * 64 + kk * 32 + lg * 8);

  f32x4 acc[4] = {};
  float mrun = -3.0e38f;
  float lrun = 0.f;

  const float MB = -10000.0f * 1.44269504f;
  bf16* pw = &Pl[w][0];

  #pragma unroll 1
  for (int kv0 = 0; kv0 < 2048; kv0 += 128) {
    // ---- stage K [128][64] + V [64][128] (32 KB), source-swizzled ----
    #pragma unroll
    for (int p = 0; p < 4; ++p) {
      int cl = p * 256 + tid;
      int krow = cl >> 3, ksch = cl & 7;
      __builtin_amdgcn_global_load_lds(
          GLP(Kp + (kv0 + krow) * 64 + (ksch ^ (krow & 7)) * 8),
          LDSP((char*)Ks + (p * 256 + w * 64) * 16), 16, 0, 0);
      int vrow = cl >> 4, vsch = cl & 15;
      __builtin_amdgcn_global_load_lds(
          GLP(Vp + vrow * 2048 + kv0 + (vsch ^ (vrow & 15)) * 8),
          LDSP((char*)Vs + (p * 256 + w * 64) * 16), 16, 0, 0);
    }
    __syncthreads();

    // swapped QK^T: sa[t], k = kv0 + t*16 + lg*4 + r, q = q16 + lr
    f32x4 sa[8];
    #pragma unroll
    for (int t = 0; t < 8; ++t) {
      f32x4 z = {};
      #pragma unroll
      for (int kk = 0; kk < 2; ++kk) {
        bf16x8 bk8 = *reinterpret_cast<const bf16x8*>(
            reinterpret_cast<const char*>(Ks) + (t * 16 + lr) * 128 + ((kk * 4 + lg) ^ (lr & 7)) * 16);
        z = __builtin_amdgcn_mfma_f32_16x16x32_bf16(bk8, aq[kk], z, 0, 0, 0);
      }
      sa[t] = z;
    }
    if (need_mask) {
      #pragma unroll
      for (int t = 0; t < 8; ++t) {
        float4 mk = *reinterpret_cast<const float4*>(mp + kv0 + t * 16 + lg * 4);
        sa[t][0] += (1.0f - mk.x) * MB;
        sa[t][1] += (1.0f - mk.y) * MB;
        sa[t][2] += (1.0f - mk.z) * MB;
        sa[t][3] += (1.0f - mk.w) * MB;
      }
    }
    // row max over 128 k's: pairwise tree + 2 cross-lane
    float rm = -3.0e38f;
    #pragma unroll
    for (int t = 0; t < 8; t += 2) {
      f32x4 mx = { fmaxf(sa[t][0], sa[t+1][0]), fmaxf(sa[t][1], sa[t+1][1]),
                   fmaxf(sa[t][2], sa[t+1][2]), fmaxf(sa[t][3], sa[t+1][3]) };
      rm = fmaxf(rm, fmaxf(fmaxf(mx[0], mx[1]), fmaxf(mx[2], mx[3])));
    }
    rm = fmaxf(rm, __shfl_xor(rm, 16));
    rm = fmaxf(rm, __shfl_xor(rm, 32));
    if (__any(rm > mrun + 8.f)) {
      float mn = fmaxf(mrun, rm);
      float fac = exp2f(mrun - mn);
      mrun = mn;
      lrun *= fac;
      float facq[4];
      #pragma unroll
      for (int r = 0; r < 4; ++r) facq[r] = __shfl(fac, ((l >> 4) << 2) + r);
      #pragma unroll
      for (int nt = 0; nt < 4; ++nt)
        #pragma unroll
        for (int r = 0; r < 4; ++r) acc[nt][r] *= facq[r];
    }
    // p = 2^(s-m), row sum
    float rs = 0.f;
    #pragma unroll
    for (int t = 0; t < 8; ++t)
      #pragma unroll
      for (int r = 0; r < 4; ++r) {
        float p = exp2f(sa[t][r] - mrun);
        sa[t][r] = p;
        rs += p;
      }
    rs += __shfl_xor(rs, 16);
    rs += __shfl_xor(rs, 32);
    lrun += rs;
    // P -> LDS: row q=lr (stride 136), col k=t*16+lg*4
    #pragma unroll
    for (int t = 0; t < 8; ++t) {
      bf16x4 pk = { (bf16)sa[t][0], (bf16)sa[t][1], (bf16)sa[t][2], (bf16)sa[t][3] };
      *reinterpret_cast<bf16x4*>(pw + lr * 136 + t * 16 + lg * 4) = pk;
    }
    asm volatile("" ::: "memory");
    // PV: ctx[q][d] += P[q][k] * V[k][d]; V from LDS (16-slot swizzle)
    #pragma unroll
    for (int ks = 0; ks < 4; ++ks) {
      bf16x8 pa = *reinterpret_cast<const bf16x8*>(
          reinterpret_cast<const char*>(pw) + lr * 272 + ks * 64 + lg * 16);
      #pragma unroll
      for (int nt = 0; nt < 4; ++nt) {
        bf16x8 bv8 = *reinterpret_cast<const bf16x8*>(
            reinterpret_cast<const char*>(Vs) + (nt * 16 + lr) * 256 + ((ks * 4 + lg) ^ lr) * 16);
        acc[nt] = __builtin_amdgcn_mfma_f32_16x16x32_bf16(pa, bv8, acc[nt], 0, 0, 0);
      }
    }
    __syncthreads();
  }

  // epilogue
  #pragma unroll
  for (int r = 0; r < 4; ++r) {
    float lq = __shfl(lrun, ((l >> 4) << 2) + r);
    float inv = 1.0f / lq;
    int sq = q16 + lg * 4 + r;
    #pragma unroll
    for (int nt = 0; nt < 4; ++nt) {
      int d = nt * 16 + lr;
      out[((bb * 2048 + sq) * 16 + hh) * 64 + d] = acc[nt][r] * inv;
    }
  }
}

extern "C" void kernel_launch(void* const* d_in, const int* in_sizes, int n_in,
                              void* d_out, int out_size, void* d_ws, size_t ws_size,
                              hipStream_t stream) {
  const float* hs   = (const float*)d_in[0];
  const float* mask = (const float*)d_in[1];
  const float* Wq   = (const float*)d_in[2];
  const float* bq   = (const float*)d_in[3];
  const float* Wk   = (const float*)d_in[4];
  const float* bk   = (const float*)d_in[5];
  const float* Wv   = (const float*)d_in[6];
  const float* bv   = (const float*)d_in[7];
  float* out = (float*)d_out;

  if (ws_size < 39845888u) return;  // need ~40 MB
  bf16* Xb = (bf16*)d_ws;
  bf16* Wb = Xb + 4194304;
  bf16* Qb = Wb + 3145728;
  bf16* Kb = Qb + 4194304;
  bf16* Vt = Kb + 4194304;

  cvt_all_kernel<<<7168, 256, 0, stream>>>(hs, Wq, Wk, Wv, Xb, Wb);
  qkv_gemm<<<dim3(24, 32), 256, 0, stream>>>(Xb, Wb, bq, bk, bv, Qb, Kb, Vt);
  attn_kernel<<<1024, 256, 0, stream>>>(Qb, Kb, Vt, mask, out);
}